// Round 4
// baseline (811.408 us; speedup 1.0000x reference)
//
#include <hip/hip_runtime.h>
#include <hip/hip_cooperative_groups.h>
#include <math.h>

namespace cg = cooperative_groups;

// Problem constants
#define BB   8
#define TT   16
#define HH   64
#define WW   64
#define GG   128          // 4*F gate channels
#define PSTR 72           // LDS fp16 row stride (64 ch + 8 pad): 144B -> chunk stride 9, coprime 8

typedef _Float16 half8 __attribute__((ext_vector_type(8)));
typedef float    f32x4 __attribute__((ext_vector_type(4)));

__device__ __forceinline__ float fast_tanh(float v) {
    float e = __expf(2.f * v);
    return 1.f - 2.f / (e + 1.f);
}
__device__ __forceinline__ float hsig(float v) {
    return fminf(fmaxf(0.2f * v + 0.5f, 0.f), 1.f);
}

// Pack weights: Wc[tap][n][ci]; ci<32 from Wx[tap][ci][n], else Wh[tap][ci-32][n]  (verified in R2/R3)
__global__ void prep_w(const float* __restrict__ Wx, const float* __restrict__ Wh,
                       _Float16* __restrict__ Wc) {
    const int k = blockIdx.x;      // 0..575 = tap*64 + ci
    const int n = threadIdx.x;     // 0..127
    const int tap = k >> 6, ci = k & 63;
    const float v = (ci < 32) ? Wx[(tap * 32 + ci) * GG + n]
                              : Wh[(tap * 32 + (ci - 32)) * GG + n];
    Wc[((size_t)tap * GG + n) * 64 + ci] = (_Float16)v;
}

// Persistent kernel: all 16 timesteps. 256 blocks x 512 threads (8 waves), 1 block/CU.
// Block tile: 8 rows x 16 cols (128 px) of one batch image, fixed across t.
// Wave (pxg = w>>2... w>>1, chg = w&1): rows {2pxg, 2pxg+1} x 64 ch.
// Channel tiles nt: ch = nt*32 + chg*16 + l15  ->  nt IS the gate index (i,f,c,o),
// feature f = chg*16 + l15. Every lane holds all 4 gates of its 8 (px,f) pairs:
// epilogue needs NO LDS exchange; c-state stays in registers across all 16 steps.
__global__ __launch_bounds__(512, 2)
void convlstm_all(const float* __restrict__ x,       // [B,T,H,W,32] fp32
                  const _Float16* __restrict__ Wc,   // [9][128][64] fp16
                  const float* __restrict__ bias,    // [128]
                  const float* __restrict__ gamma_,  // [32]
                  const float* __restrict__ beta_,   // [32]
                  const float* __restrict__ mmean,   // [32]
                  const float* __restrict__ mvar,    // [32]
                  _Float16* __restrict__ h0,         // [B,H,W,32] fp16 (zeroed)
                  _Float16* __restrict__ h1,         // [B,H,W,32] fp16
                  float* __restrict__ out)           // [B,T,H,W,32] fp32
{
    __shared__ _Float16 patch[180 * PSTR];     // 25.9 KB: 10x18 halo pos x (32 x-ch | 32 h-ch)
    __shared__ _Float16 wbuf[2][GG * PSTR];    // 36.9 KB: double-buffered per-tap weights

    cg::grid_group grid = cg::this_grid();

    const int tid  = threadIdx.x;
    const int lane = tid & 63;
    const int w    = tid >> 6;       // wave 0..7
    const int l15  = lane & 15;
    const int quad = lane >> 4;
    const int chg  = w & 1;
    const int pxg  = w >> 1;         // 0..3
    const int blk  = blockIdx.x;
    const int b    = blk >> 5;
    const int ty   = (blk >> 2) & 7;
    const int tx   = blk & 3;
    const int py0  = ty * 8;
    const int px0  = tx * 16;

    // per-lane feature + BN constants + bias (fixed across t)
    const int f = chg * 16 + l15;
    const float inv = gamma_[f] * rsqrtf(mvar[f] + 1e-3f);
    const float bnb = beta_[f] - mmean[f] * inv;
    float binit[4];
    #pragma unroll
    for (int nt = 0; nt < 4; ++nt) binit[nt] = bias[nt * 32 + f];

    // c-state in registers for the whole sequence: [mt][r]
    float creg[2][4] = {{0.f, 0.f, 0.f, 0.f}, {0.f, 0.f, 0.f, 0.f}};

    for (int t = 0; t < TT; ++t) {
        const _Float16* hc = (t & 1) ? h1 : h0;
        _Float16*       hn = (t & 1) ? h0 : h1;
        if (t) grid.sync();    // h[t-1] writes visible to all blocks; also block-level barrier

        // ---- stage x patch: 180 pos x 4 chunks of 8 ch (fp32 -> fp16) ----
        const float* xt = x + (((size_t)b * TT + t) * HH * WW) * 32;
        for (int i = tid; i < 720; i += 512) {
            const int pos = i >> 2;
            const int q   = i & 3;
            const int row = pos / 18;
            const int col = pos - row * 18;
            const int gy = py0 + row - 1;
            const int gx = px0 + col - 1;
            half8 hv = {0, 0, 0, 0, 0, 0, 0, 0};
            if ((unsigned)gy < HH && (unsigned)gx < WW) {
                const float* s = xt + ((size_t)(gy * WW + gx)) * 32 + q * 8;
                const float4 v0 = *(const float4*)s;
                const float4 v1 = *(const float4*)(s + 4);
                hv = (half8){(_Float16)v0.x, (_Float16)v0.y, (_Float16)v0.z, (_Float16)v0.w,
                             (_Float16)v1.x, (_Float16)v1.y, (_Float16)v1.z, (_Float16)v1.w};
            }
            *(half8*)&patch[pos * PSTR + q * 8] = hv;
        }
        // ---- stage h patch (fp16) ----
        const _Float16* hb = hc + (size_t)b * HH * WW * 32;
        for (int i = tid; i < 720; i += 512) {
            const int pos = i >> 2;
            const int q   = i & 3;
            const int row = pos / 18;
            const int col = pos - row * 18;
            const int gy = py0 + row - 1;
            const int gx = px0 + col - 1;
            half8 hv = {0, 0, 0, 0, 0, 0, 0, 0};
            if ((unsigned)gy < HH && (unsigned)gx < WW)
                hv = *(const half8*)(hb + ((size_t)(gy * WW + gx)) * 32 + q * 8);
            *(half8*)&patch[pos * PSTR + 32 + q * 8] = hv;
        }
        // ---- stage tap-0 weights ----
        #pragma unroll
        for (int i = 0; i < 2; ++i) {
            const int c = tid + i * 512;          // 1024 chunks of 16B
            const int n = c >> 3, sub = c & 7;
            *(uint4*)&wbuf[0][n * PSTR + sub * 8] = *(const uint4*)(Wc + (size_t)n * 64 + sub * 8);
        }
        __syncthreads();

        f32x4 acc[2][4];
        #pragma unroll
        for (int mt = 0; mt < 2; ++mt)
            #pragma unroll
            for (int nt = 0; nt < 4; ++nt)
                acc[mt][nt] = (f32x4){binit[nt], binit[nt], binit[nt], binit[nt]};

        // ---- K loop: 9 taps x 2 ksteps (K=32: x-half then h-half) ----
        for (int tap = 0; tap < 9; ++tap) {
            const int buf = tap & 1;
            uint4 pre[2];
            if (tap < 8) {
                const _Float16* wsrc = Wc + (size_t)(tap + 1) * GG * 64;
                #pragma unroll
                for (int i = 0; i < 2; ++i) {
                    const int c = tid + i * 512;
                    pre[i] = *(const uint4*)(wsrc + (size_t)(c >> 3) * 64 + (c & 7) * 8);
                }
            }
            const int ky = tap / 3;
            const int kx = tap - ky * 3;

            #pragma unroll
            for (int hk = 0; hk < 2; ++hk) {
                const int ci0 = hk * 32 + quad * 8;
                const half8 a0 = *(const half8*)&patch[((2 * pxg + 0 + ky) * 18 + l15 + kx) * PSTR + ci0];
                const half8 a1 = *(const half8*)&patch[((2 * pxg + 1 + ky) * 18 + l15 + kx) * PSTR + ci0];
                half8 bfr[4];
                #pragma unroll
                for (int nt = 0; nt < 4; ++nt)
                    bfr[nt] = *(const half8*)&wbuf[buf][(nt * 32 + chg * 16 + l15) * PSTR + ci0];
                #pragma unroll
                for (int nt = 0; nt < 4; ++nt) {
                    acc[0][nt] = __builtin_amdgcn_mfma_f32_16x16x32_f16(a0, bfr[nt], acc[0][nt], 0, 0, 0);
                    acc[1][nt] = __builtin_amdgcn_mfma_f32_16x16x32_f16(a1, bfr[nt], acc[1][nt], 0, 0, 0);
                }
            }
            if (tap < 8) {
                #pragma unroll
                for (int i = 0; i < 2; ++i) {
                    const int c = tid + i * 512;
                    *(uint4*)&wbuf[1 - buf][(c >> 3) * PSTR + (c & 7) * 8] = pre[i];
                }
            }
            __syncthreads();
        }

        // ---- epilogue: lane owns 8 (px, f) pairs with ALL 4 gates in acc[mt][nt=gate][r] ----
        float* op = out + (((size_t)b * TT + t) * HH * WW) * 32;
        _Float16* hq = hn + (size_t)b * HH * WW * 32;
        #pragma unroll
        for (int mt = 0; mt < 2; ++mt) {
            const int gy = py0 + 2 * pxg + mt;
            #pragma unroll
            for (int r = 0; r < 4; ++r) {
                const int gx = px0 + quad * 4 + r;
                const size_t pix = (size_t)(gy * WW + gx);
                const float gi = acc[mt][0][r];
                const float gf = acc[mt][1][r];
                const float gc = acc[mt][2][r];
                const float go = acc[mt][3][r];
                const float cn = hsig(gf) * creg[mt][r] + hsig(gi) * fast_tanh(gc);
                const float hv = hsig(go) * fast_tanh(cn);
                creg[mt][r] = cn;
                hq[pix * 32 + f] = (_Float16)hv;
                op[pix * 32 + f] = hv * inv + bnb;
            }
        }
    }
}

extern "C" void kernel_launch(void* const* d_in, const int* in_sizes, int n_in,
                              void* d_out, int out_size, void* d_ws, size_t ws_size,
                              hipStream_t stream)
{
    const float* x      = (const float*)d_in[0];
    const float* Wx     = (const float*)d_in[1];
    const float* Wh     = (const float*)d_in[2];
    const float* bias   = (const float*)d_in[3];
    const float* gamma_ = (const float*)d_in[4];
    const float* beta_  = (const float*)d_in[5];
    const float* mmean  = (const float*)d_in[6];
    const float* mvar   = (const float*)d_in[7];
    float* out = (float*)d_out;

    // ws layout: [h0 fp16 2MB][h1 fp16 2MB][Wc fp16 147KB]  (~4.2 MB total)
    char* wsb = (char*)d_ws;
    _Float16* h0 = (_Float16*)wsb;
    _Float16* h1 = (_Float16*)(wsb + (2 << 20));
    _Float16* Wc = (_Float16*)(wsb + (4 << 20));

    hipMemsetAsync(d_ws, 0, (size_t)2 << 20, stream);          // zero h0
    prep_w<<<dim3(576), dim3(128), 0, stream>>>(Wx, Wh, Wc);

    void* args[] = {(void*)&x, (void*)&Wc, (void*)&bias, (void*)&gamma_, (void*)&beta_,
                    (void*)&mmean, (void*)&mvar, (void*)&h0, (void*)&h1, (void*)&out};
    hipLaunchCooperativeKernel((void*)convlstm_all, dim3(256), dim3(512), args, 0, stream);
}

// Round 5
// 422.998 us; speedup vs baseline: 1.9182x; 1.9182x over previous
//
#include <hip/hip_runtime.h>
#include <math.h>

// Problem constants
#define PSTR 40     // LDS fp16 patch row stride: 80 B (16B-aligned, uniform banks)

typedef _Float16 half8 __attribute__((ext_vector_type(8)));
typedef float    f32x4 __attribute__((ext_vector_type(4)));

__device__ __forceinline__ float fast_tanh(float v) {
    float e = __expf(2.f * v);
    return 1.f - 2.f / (e + 1.f);
}
__device__ __forceinline__ float hsig(float v) {
    return fminf(fmaxf(0.2f * v + 0.5f, 0.f), 1.f);
}

// Pack weights: Wcx[tap][n][ci<32] from Wx[tap][ci][n]; Wch[tap][n][ci] from Wh[tap][ci][n]
__global__ void prep_w(const float* __restrict__ Wx, const float* __restrict__ Wh,
                       _Float16* __restrict__ Wcx, _Float16* __restrict__ Wch) {
    const int k = blockIdx.x;      // 0..575 = tap*64 + ci
    const int n = threadIdx.x;     // 0..127
    const int tap = k >> 6, ci = k & 63;
    if (ci < 32) Wcx[(tap * 128 + n) * 32 + ci]        = (_Float16)Wx[(tap * 32 + ci) * 128 + n];
    else         Wch[(tap * 128 + n) * 32 + (ci - 32)] = (_Float16)Wh[(tap * 32 + (ci - 32)) * 128 + n];
}

// ---- Parallel x-conv GEMM: xg[b,t] = conv3x3(x_t, Wx) + bias, fp16, lane-swizzled ----
// Grid (8,8,16): 8x8 px tile per (b, t0+lt) image; 256 threads, 4 waves.
// Wave (chg=w&1, mtg=w>>1): 32 px x 64 ch. acc[mt][nt]: px=(mtg*2+mt)*16+quad*4+r,
// ch = nt*32 + chg*16 + l15  (nt = gate, f = chg*16+l15). B-frags direct from L2.
__global__ __launch_bounds__(256, 4)
void xgemm(const float* __restrict__ x, const _Float16* __restrict__ Wcx,
           const float* __restrict__ bias, _Float16* __restrict__ xg, int t0)
{
    __shared__ _Float16 patch[100 * PSTR];   // 8 KB: 10x10 halo x 32 ch

    const int tid  = threadIdx.x;
    const int lane = tid & 63;
    const int w    = tid >> 6;
    const int l15  = lane & 15, quad = lane >> 4;
    const int chg  = w & 1, mtg = w >> 1;
    const int tx = blockIdx.x, ty = blockIdx.y, z = blockIdx.z;
    const int b = z >> 1, t = t0 + (z & 1);
    const int px0 = tx * 8, py0 = ty * 8;

    // stage x patch (fp32 -> fp16)
    const float* xt = x + (((size_t)b * 16 + t) * 4096) * 32;
    for (int i = tid; i < 400; i += 256) {
        const int pos = i >> 2, q = i & 3;
        const int row = pos / 10, col = pos - row * 10;
        const int gy = py0 + row - 1, gx = px0 + col - 1;
        half8 hv = {0, 0, 0, 0, 0, 0, 0, 0};
        if ((unsigned)gy < 64u && (unsigned)gx < 64u) {
            const float* s = xt + ((size_t)(gy * 64 + gx)) * 32 + q * 8;
            const float4 v0 = *(const float4*)s;
            const float4 v1 = *(const float4*)(s + 4);
            hv = (half8){(_Float16)v0.x, (_Float16)v0.y, (_Float16)v0.z, (_Float16)v0.w,
                         (_Float16)v1.x, (_Float16)v1.y, (_Float16)v1.z, (_Float16)v1.w};
        }
        *(half8*)&patch[pos * PSTR + q * 8] = hv;
    }
    __syncthreads();

    const int f = chg * 16 + l15;
    float bi[4];
    #pragma unroll
    for (int nt = 0; nt < 4; ++nt) bi[nt] = bias[nt * 32 + f];

    f32x4 acc[2][4];
    #pragma unroll
    for (int mt = 0; mt < 2; ++mt)
        #pragma unroll
        for (int nt = 0; nt < 4; ++nt)
            acc[mt][nt] = (f32x4){bi[nt], bi[nt], bi[nt], bi[nt]};

    const int pbase = ((mtg * 4 + (l15 >> 3)) * 10 + (l15 & 7)) * PSTR + quad * 8;
    const _Float16* wb = Wcx + (chg * 16 + l15) * 32 + quad * 8;

    #pragma unroll
    for (int tap = 0; tap < 9; ++tap) {
        const int ky = tap / 3, kx = tap - ky * 3;
        const half8 a0 = *(const half8*)&patch[pbase + (ky * 10 + kx) * PSTR];
        const half8 a1 = *(const half8*)&patch[pbase + (ky * 10 + kx + 20) * PSTR];
        #pragma unroll
        for (int nt = 0; nt < 4; ++nt) {
            const half8 bf = *(const half8*)(wb + tap * 4096 + nt * 1024);
            acc[0][nt] = __builtin_amdgcn_mfma_f32_16x16x32_f16(a0, bf, acc[0][nt], 0, 0, 0);
            acc[1][nt] = __builtin_amdgcn_mfma_f32_16x16x32_f16(a1, bf, acc[1][nt], 0, 0, 0);
        }
    }

    // write lane-contiguous: 32 fp16 = 64 B per lane, order [mt][nt][r]
    half8 hv[4];
    #pragma unroll
    for (int mt = 0; mt < 2; ++mt)
        #pragma unroll
        for (int nt = 0; nt < 4; ++nt)
            #pragma unroll
            for (int r = 0; r < 4; ++r)
                hv[mt * 2 + (nt >> 1)][(nt & 1) * 4 + r] = (_Float16)acc[mt][nt][r];
    _Float16* dst = xg + (((size_t)z * 64 + ty * 8 + tx) * 256 + tid) * 32;
    #pragma unroll
    for (int j = 0; j < 4; ++j) *(half8*)(dst + j * 8) = hv[j];
}

// ---- Sequential step: h-conv + xg + LSTM + BN. Same tile/lane mapping as xgemm. ----
__global__ __launch_bounds__(256, 4)
void hstep(const _Float16* __restrict__ xg, const _Float16* __restrict__ Wch,
           const float* __restrict__ gamma_, const float* __restrict__ beta_,
           const float* __restrict__ mmean, const float* __restrict__ mvar,
           const _Float16* __restrict__ hprev, _Float16* __restrict__ hnext,
           float* __restrict__ csw, float* __restrict__ out, int t)
{
    __shared__ _Float16 patch[100 * PSTR];   // 8 KB: 10x10 halo x 32 h-ch

    const int tid  = threadIdx.x;
    const int lane = tid & 63;
    const int w    = tid >> 6;
    const int l15  = lane & 15, quad = lane >> 4;
    const int chg  = w & 1, mtg = w >> 1;
    const int tx = blockIdx.x, ty = blockIdx.y, b = blockIdx.z;
    const int px0 = tx * 8, py0 = ty * 8;
    const int tile = ty * 8 + tx;

    // stage h patch (fp16)
    const _Float16* hb = hprev + (size_t)b * 4096 * 32;
    for (int i = tid; i < 400; i += 256) {
        const int pos = i >> 2, q = i & 3;
        const int row = pos / 10, col = pos - row * 10;
        const int gy = py0 + row - 1, gx = px0 + col - 1;
        half8 hv = {0, 0, 0, 0, 0, 0, 0, 0};
        if ((unsigned)gy < 64u && (unsigned)gx < 64u)
            hv = *(const half8*)(hb + ((size_t)(gy * 64 + gx)) * 32 + q * 8);
        *(half8*)&patch[pos * PSTR + q * 8] = hv;
    }
    __syncthreads();

    f32x4 acc[2][4];
    #pragma unroll
    for (int mt = 0; mt < 2; ++mt)
        #pragma unroll
        for (int nt = 0; nt < 4; ++nt)
            acc[mt][nt] = (f32x4){0.f, 0.f, 0.f, 0.f};

    const int pbase = ((mtg * 4 + (l15 >> 3)) * 10 + (l15 & 7)) * PSTR + quad * 8;
    const _Float16* wb = Wch + (chg * 16 + l15) * 32 + quad * 8;

    #pragma unroll
    for (int tap = 0; tap < 9; ++tap) {
        const int ky = tap / 3, kx = tap - ky * 3;
        const half8 a0 = *(const half8*)&patch[pbase + (ky * 10 + kx) * PSTR];
        const half8 a1 = *(const half8*)&patch[pbase + (ky * 10 + kx + 20) * PSTR];
        #pragma unroll
        for (int nt = 0; nt < 4; ++nt) {
            const half8 bf = *(const half8*)(wb + tap * 4096 + nt * 1024);
            acc[0][nt] = __builtin_amdgcn_mfma_f32_16x16x32_f16(a0, bf, acc[0][nt], 0, 0, 0);
            acc[1][nt] = __builtin_amdgcn_mfma_f32_16x16x32_f16(a1, bf, acc[1][nt], 0, 0, 0);
        }
    }

    // ---- epilogue: xg (lane-contiguous 64 B), c (lane-contiguous 32 B), LSTM, BN ----
    const _Float16* xgp = xg + (((size_t)(b * 2 + (t & 1)) * 64 + tile) * 256 + tid) * 32;
    half8 xv[4];
    #pragma unroll
    for (int j = 0; j < 4; ++j) xv[j] = *(const half8*)(xgp + j * 8);

    float* cp = csw + (((size_t)b * 64 + tile) * 256 + tid) * 8;
    f32x4 cold0 = *(const f32x4*)cp;
    f32x4 cold1 = *(const f32x4*)(cp + 4);

    const int f = chg * 16 + l15;
    const float inv = gamma_[f] * rsqrtf(mvar[f] + 1e-3f);
    const float bnb = beta_[f] - mmean[f] * inv;

    _Float16* hq = hnext + (size_t)b * 4096 * 32;
    float* oq = out + (((size_t)b * 16 + t) * 4096) * 32;

    f32x4 cn0, cn1;
    #pragma unroll
    for (int mt = 0; mt < 2; ++mt) {
        #pragma unroll
        for (int r = 0; r < 4; ++r) {
            const int px = (mtg * 2 + mt) * 16 + quad * 4 + r;
            const int gy = py0 + (px >> 3), gx = px0 + (px & 7);
            // xg order [mt][nt][r]: chunk = mt*2+(nt>>1), elem = (nt&1)*4+r
            const float gi = acc[mt][0][r] + (float)xv[mt * 2 + 0][0 + r];
            const float gf = acc[mt][1][r] + (float)xv[mt * 2 + 0][4 + r];
            const float gc = acc[mt][2][r] + (float)xv[mt * 2 + 1][0 + r];
            const float go = acc[mt][3][r] + (float)xv[mt * 2 + 1][4 + r];
            const float co = mt ? cold1[r] : cold0[r];
            const float cn = hsig(gf) * co + hsig(gi) * fast_tanh(gc);
            const float hv = hsig(go) * fast_tanh(cn);
            if (mt) cn1[r] = cn; else cn0[r] = cn;
            const size_t pix = ((size_t)(gy * 64 + gx)) * 32 + f;
            hq[pix] = (_Float16)hv;
            oq[pix] = hv * inv + bnb;
        }
    }
    *(f32x4*)cp       = cn0;
    *(f32x4*)(cp + 4) = cn1;
}

extern "C" void kernel_launch(void* const* d_in, const int* in_sizes, int n_in,
                              void* d_out, int out_size, void* d_ws, size_t ws_size,
                              hipStream_t stream)
{
    const float* x      = (const float*)d_in[0];
    const float* Wx     = (const float*)d_in[1];
    const float* Wh     = (const float*)d_in[2];
    const float* bias   = (const float*)d_in[3];
    const float* gamma_ = (const float*)d_in[4];
    const float* beta_  = (const float*)d_in[5];
    const float* mmean  = (const float*)d_in[6];
    const float* mvar   = (const float*)d_in[7];
    float* out = (float*)d_out;

    // ws: [h0 2MB][csw 4MB][h1 2MB][xg 16.78MB][Wcx 73.7KB][Wch 73.7KB] = 25.3 MB
    char* wsb = (char*)d_ws;
    _Float16* h0  = (_Float16*)(wsb);
    float*    csw = (float*)(wsb + 2097152);
    _Float16* h1  = (_Float16*)(wsb + 6291456);
    _Float16* xg  = (_Float16*)(wsb + 8388608);
    _Float16* Wcx = (_Float16*)(wsb + 25165824);
    _Float16* Wch = (_Float16*)(wsb + 25239552);

    hipMemsetAsync(d_ws, 0, 6291456, stream);   // zero h0 + csw
    prep_w<<<dim3(576), dim3(128), 0, stream>>>(Wx, Wh, Wcx, Wch);

    dim3 gg(8, 8, 16);   // xgemm: 2 timesteps x 8 batches
    dim3 gs(8, 8, 8);    // hstep: 1 timestep
    _Float16* hp = h0;
    _Float16* hn = h1;
    for (int c = 0; c < 8; ++c) {
        xgemm<<<gg, 256, 0, stream>>>(x, Wcx, bias, xg, 2 * c);
        for (int k = 0; k < 2; ++k) {
            const int t = 2 * c + k;
            hstep<<<gs, 256, 0, stream>>>(xg, Wch, gamma_, beta_, mmean, mvar,
                                          hp, hn, csw, out, t);
            _Float16* tmp = hp; hp = hn; hn = tmp;
        }
    }
}